// Round 7
// baseline (45960.831 us; speedup 1.0000x reference)
//
#include <hip/hip_runtime.h>
#include <hip/hip_bf16.h>
#include <math.h>

#define T_STEPS 2048
#define N_MOD   64
#define N_HID   256
#define N_INP   128
#define S_STEPS 4     // steps fused per launch; T_STEPS % S_STEPS == 0

typedef unsigned long long ull;

// Relaxed agent-scope (sc1) ops: bypass L1/L2, coherent at LLC across XCDs.
// NO acquire fences anywhere in the step kernels — agent-acquire emits
// buffer_inv which would evict the L2-resident h2h/wm weights (R1-R5 lesson).
__device__ __forceinline__ float AG_LDF(const float* p) {
  return __hip_atomic_load(p, __ATOMIC_RELAXED, __HIP_MEMORY_SCOPE_AGENT);
}
__device__ __forceinline__ void AG_STF(float* p, float v) {
  __hip_atomic_store(p, v, __ATOMIC_RELAXED, __HIP_MEMORY_SCOPE_AGENT);
}

// --------------------------------------------------------------------------
// init: states_seq[0] = initial_states
// --------------------------------------------------------------------------
__global__ __launch_bounds__(512) void init_kernel(
    const float* __restrict__ init, float* __restrict__ out_states)
{
  const int idx = blockIdx.x * 512 + threadIdx.x;   // 64*512 = 32768 elems
  out_states[idx] = init[idx];
}

// --------------------------------------------------------------------------
// Pre-pass: xpre[t,n,h] = sum_i x2h[n,h,i] * x[t,i]  -> fb_seq region of d_out.
// Step kernels read xpre[t] (prefetched at kernel start, before any fb
// overwrite of those addresses) then overwrite with fb[t].
// --------------------------------------------------------------------------
__global__ __launch_bounds__(256, 2) void xpre_kernel(
    const float* __restrict__ x, const float* __restrict__ x2h,
    float* __restrict__ out)
{
  __shared__ float xl[64 * N_INP];
  const int tb = blockIdx.x;
  const int n  = blockIdx.y;
  const int t  = threadIdx.x;

  const float4* xs  = (const float4*)(x + (size_t)tb * 64 * N_INP);
  float4*       xld = (float4*)xl;
  for (int k = t; k < 64 * N_INP / 4; k += 256) xld[k] = xs[k];

  float w[N_INP];
  const float* wrow = x2h + ((size_t)n * N_HID + t) * N_INP;
#pragma unroll
  for (int j = 0; j < N_INP; j += 4) {
    const float4 a = *(const float4*)(wrow + j);
    w[j] = a.x; w[j+1] = a.y; w[j+2] = a.z; w[j+3] = a.w;
  }
  __syncthreads();

  for (int tt = 0; tt < 64; ++tt) {
    float a0=0.f, a1=0.f, a2=0.f, a3=0.f;
#pragma unroll
    for (int j = 0; j < N_INP; j += 4) {
      const float4 h4 = *(const float4*)&xl[tt * N_INP + j];
      a0 = fmaf(w[j],   h4.x, a0);
      a1 = fmaf(w[j+1], h4.y, a1);
      a2 = fmaf(w[j+2], h4.z, a2);
      a3 = fmaf(w[j+3], h4.w, a3);
    }
    out[((size_t)(tb*64 + tt) * N_MOD + n) * N_HID + t] = (a0+a1)+(a2+a3);
  }
}

// --------------------------------------------------------------------------
// Fused S_STEPS-per-launch step kernel (cooperative, 256 WGs x 256 thr,
// 1 WG/CU). WG (m=b>>2, q=b&3) owns rows [q*64, q*64+64) of module m.
// Thread i: ro=i&63, jq=i>>6 (64-wide j-chunk).
//
// u-formulation: fb[m] = wm @ u[m], u[m,j] = sum_mm conn[m,mm]*hy_k[mm,j];
// r and f matvecs are independent -> dual-issue in one phase.
//
// Per internal step: phase1 gather {hym, u} (sc1 for internal steps),
// phase2 dual quarter-row matvecs, phase3 (wave 0) reduce + tanh Euler +
// sc1-publish hy/hz + plain-store fb.
// Internal barrier (between steps only): wave0's stores are ordered by the
// acq_rel atomicAdd (same wave, vmcnt drain); one thread/WG arrives on
// ctr[k] and spins relaxed+s_sleep until 256; __syncthreads() releases the
// WG. No fences -> no buffer_inv -> h2h/wm stay L2-resident. Readers use
// sc1 loads so stale caches are impossible.
// hy/hz/bias/xpre persist in wave-0 registers across the S internal steps.
// --------------------------------------------------------------------------
__global__ __launch_bounds__(256) void step4_kernel(
    int k0, const float* __restrict__ wm, const float* __restrict__ conn,
    const float* __restrict__ h2h, const float* __restrict__ bias,
    float* __restrict__ out_states, float* __restrict__ out_fb,
    unsigned* __restrict__ ctr)
{
  const int b  = blockIdx.x;
  const int m  = b >> 2;
  const int q  = b & 3;
  const int i  = threadIdx.x;       // 0..255
  const int ro = i & 63;
  const int jq = i >> 6;

  __shared__ float hym[N_HID];
  __shared__ float u[N_HID];
  __shared__ float redr[256];
  __shared__ float redf[256];
  __shared__ float connrow[N_MOD];

  if (i < N_MOD) connrow[i] = conn[m * N_MOD + i];

  // ---- wave-0 persistent step state ----
  const int hu = q * 64 + ro;
  float hyv = 0.f, hzv = 0.f, bv = 0.f;
  float xqs[S_STEPS];
  if (i < 64) {
    const float* s0 = out_states + (size_t)k0 * N_MOD * 512 + (size_t)m * 512;
    hyv = s0[hu];
    hzv = s0[256 + hu];
    bv  = bias[m * N_HID + hu];
#pragma unroll
    for (int s = 0; s < S_STEPS; ++s)
      xqs[s] = out_fb[((size_t)(k0 + s) * N_MOD + m) * N_HID + hu];
  }

#pragma unroll
  for (int sidx = 0; sidx < S_STEPS; ++sidx) {
    const int k = k0 + sidx;
    const float* hyk = out_states + (size_t)k * N_MOD * 512;

    // ---- phase 1: hym + u gather ----
    if (sidx == 0) {
      hym[i] = hyk[(size_t)m * 512 + i];          // plain: prev-kernel data
      float ua=0.f, ub=0.f, uc=0.f, ud=0.f;
#pragma unroll
      for (int mm = 0; mm < N_MOD; mm += 4) {
        ua = fmaf(connrow[mm+0], hyk[(size_t)(mm+0) * 512 + i], ua);
        ub = fmaf(connrow[mm+1], hyk[(size_t)(mm+1) * 512 + i], ub);
        uc = fmaf(connrow[mm+2], hyk[(size_t)(mm+2) * 512 + i], uc);
        ud = fmaf(connrow[mm+3], hyk[(size_t)(mm+3) * 512 + i], ud);
      }
      u[i] = (ua + ub) + (uc + ud);
    } else {
      hym[i] = AG_LDF(&hyk[(size_t)m * 512 + i]); // sc1: intra-kernel data
      float ua=0.f, ub=0.f, uc=0.f, ud=0.f;
#pragma unroll
      for (int mm = 0; mm < N_MOD; mm += 4) {
        ua = fmaf(connrow[mm+0], AG_LDF(&hyk[(size_t)(mm+0) * 512 + i]), ua);
        ub = fmaf(connrow[mm+1], AG_LDF(&hyk[(size_t)(mm+1) * 512 + i]), ub);
        uc = fmaf(connrow[mm+2], AG_LDF(&hyk[(size_t)(mm+2) * 512 + i]), uc);
        ud = fmaf(connrow[mm+3], AG_LDF(&hyk[(size_t)(mm+3) * 512 + i]), ud);
      }
      u[i] = (ua + ub) + (uc + ud);
    }
    __syncthreads();

    // ---- phase 2: dual quarter-row matvecs (weights stay L2-resident) ----
    {
      const int h = q * 64 + ro;
      const float* hrow = h2h + ((size_t)m * N_HID + h) * N_HID + jq * 64;
      const float* wrow = wm  + (size_t)h * N_HID + jq * 64;
      float r0=0.f, r1=0.f, r2=0.f, r3=0.f;
      float f0=0.f, f1=0.f, f2=0.f, f3=0.f;
#pragma unroll
      for (int j = 0; j < 64; j += 4) {
        const float4 a  = *(const float4*)(hrow + j);
        const float4 w4 = *(const float4*)(wrow + j);
        const float4 hv = *(const float4*)(&hym[jq * 64 + j]);
        const float4 uv = *(const float4*)(&u[jq * 64 + j]);
        r0 = fmaf(a.x, hv.x, r0);  f0 = fmaf(w4.x, uv.x, f0);
        r1 = fmaf(a.y, hv.y, r1);  f1 = fmaf(w4.y, uv.y, f1);
        r2 = fmaf(a.z, hv.z, r2);  f2 = fmaf(w4.z, uv.z, f2);
        r3 = fmaf(a.w, hv.w, r3);  f3 = fmaf(w4.w, uv.w, f3);
      }
      redr[i] = (r0 + r1) + (r2 + r3);
      redf[i] = (f0 + f1) + (f2 + f3);
    }
    __syncthreads();

    // ---- phase 3: wave 0 — reduce, update, publish ----
    if (i < 64) {
      const float r  = (redr[ro] + redr[ro + 64]) + (redr[ro + 128] + redr[ro + 192]);
      const float fb = (k == 0) ? 0.f
                     : (redf[ro] + redf[ro + 64]) + (redf[ro + 128] + redf[ro + 192]);
      const float pre = xqs[sidx] + r + bv + fb;
      const float th  = tanhf(pre);
      hzv = hzv + 0.01f * (th - hyv - hzv);     // GAMMA=EPS=1, DT=0.01
      hyv = hyv + 0.01f * hzv;
      float* o1 = out_states + (size_t)(k + 1) * N_MOD * 512 + (size_t)m * 512;
      AG_STF(&o1[hu], hyv);                     // sc1: visible via LLC
      AG_STF(&o1[256 + hu], hzv);
      out_fb[((size_t)k * N_MOD + m) * N_HID + hu] = fb;   // overwrite xpre[k]
    }

    // ---- internal grid barrier (not after the last step) ----
    if (sidx < S_STEPS - 1) {
      if (i == 0) {
        // acq_rel add: drains wave-0's sc1 stores (vmcnt) before arriving
        __hip_atomic_fetch_add(&ctr[k], 1u, __ATOMIC_ACQ_REL,
                               __HIP_MEMORY_SCOPE_AGENT);
        while (__hip_atomic_load(&ctr[k], __ATOMIC_RELAXED,
                                 __HIP_MEMORY_SCOPE_AGENT) < 256u)
          __builtin_amdgcn_s_sleep(2);
      }
      __syncthreads();   // releases WG; compiler memory barrier (no hoisting)
    }
  }
}

// --------------------------------------------------------------------------
extern "C" void kernel_launch(void* const* d_in, const int* in_sizes, int n_in,
                              void* d_out, int out_size, void* d_ws, size_t ws_size,
                              hipStream_t stream) {
  const float* x    = (const float*)d_in[0];   // (2048,128)
  const float* init = (const float*)d_in[1];   // (64,2,256)
  const float* wmw  = (const float*)d_in[2];   // (256,256)
  const float* conn = (const float*)d_in[3];   // (64,64)
  const float* x2h  = (const float*)d_in[4];   // (64,256,128)
  const float* h2h  = (const float*)d_in[5];   // (64,256,256)
  const float* bias = (const float*)d_in[6];   // (64,256)

  float* out_states = (float*)d_out;                                        // (2049,64,2,256)
  float* out_fb     = out_states + (size_t)(T_STEPS+1) * N_MOD * 2 * N_HID; // (2048,64,256)

  // workspace: per-step barrier counters, zeroed every launch (replay-safe)
  unsigned* ctr = (unsigned*)d_ws;
  hipMemsetAsync(d_ws, 0, (size_t)T_STEPS * sizeof(unsigned), stream);

  init_kernel<<<64, 512, 0, stream>>>(init, out_states);
  xpre_kernel<<<dim3(T_STEPS/64, N_MOD), dim3(256), 0, stream>>>(x, x2h, out_fb);

  for (int k0 = 0; k0 < T_STEPS; k0 += S_STEPS) {
    void* args[] = {
      (void*)&k0, (void*)&wmw, (void*)&conn, (void*)&h2h, (void*)&bias,
      (void*)&out_states, (void*)&out_fb, (void*)&ctr
    };
    hipLaunchCooperativeKernel((void*)step4_kernel, dim3(256), dim3(256),
                               args, 0, stream);
  }
}

// Round 9
// 14990.042 us; speedup vs baseline: 3.0661x; 3.0661x over previous
//
#include <hip/hip_runtime.h>
#include <hip/hip_bf16.h>
#include <math.h>

#define T_STEPS 2048
#define N_MOD   64
#define N_HID   256
#define N_INP   128

// Relaxed-ONLY agent-scope (sc1) ops. No acquire/release/acq_rel anywhere in
// the persistent kernel: agent-acquire emits cache invalidates (R1 spin-acq,
// R7 acq_rel barrier = ~25us each) which evict the L2-resident weights.
// Release ordering = s_waitcnt vmcnt(0) (sc1 stores ACK at the LLC coherence
// point, so waitcnt-then-RMW orders publish before arrive).
__device__ __forceinline__ void AG_STF(float* p, float v) {
  __hip_atomic_store(p, v, __ATOMIC_RELAXED, __HIP_MEMORY_SCOPE_AGENT);
}
__device__ __forceinline__ unsigned AG_ADD(unsigned* p, unsigned v) {
  return __hip_atomic_fetch_add(p, v, __ATOMIC_RELAXED, __HIP_MEMORY_SCOPE_AGENT);
}
__device__ __forceinline__ unsigned AG_LDU(const unsigned* p) {
  return __hip_atomic_load(p, __ATOMIC_RELAXED, __HIP_MEMORY_SCOPE_AGENT);
}

// --------------------------------------------------------------------------
// init: states_seq[0] = initial_states
// --------------------------------------------------------------------------
__global__ __launch_bounds__(512) void init_kernel(
    const float* __restrict__ init, float* __restrict__ out_states)
{
  const int idx = blockIdx.x * 512 + threadIdx.x;   // 64*512 = 32768 elems
  out_states[idx] = init[idx];
}

// --------------------------------------------------------------------------
// Pre-pass: xpre[t,n,h] = sum_i x2h[n,h,i] * x[t,i]  -> fb_seq region of d_out.
// The persistent kernel reads xpre[t] then overwrites it with fb[t]
// (same thread, read-before-write -> deterministic across replays; xpre is
// re-established at the start of every kernel_launch/replay).
// --------------------------------------------------------------------------
__global__ __launch_bounds__(256, 2) void xpre_kernel(
    const float* __restrict__ x, const float* __restrict__ x2h,
    float* __restrict__ out)
{
  __shared__ float xl[64 * N_INP];
  const int tb = blockIdx.x;
  const int n  = blockIdx.y;
  const int t  = threadIdx.x;

  const float4* xs  = (const float4*)(x + (size_t)tb * 64 * N_INP);
  float4*       xld = (float4*)xl;
  for (int k = t; k < 64 * N_INP / 4; k += 256) xld[k] = xs[k];

  float w[N_INP];
  const float* wrow = x2h + ((size_t)n * N_HID + t) * N_INP;
#pragma unroll
  for (int j = 0; j < N_INP; j += 4) {
    const float4 a = *(const float4*)(wrow + j);
    w[j] = a.x; w[j+1] = a.y; w[j+2] = a.z; w[j+3] = a.w;
  }
  __syncthreads();

  for (int tt = 0; tt < 64; ++tt) {
    float a0=0.f, a1=0.f, a2=0.f, a3=0.f;
#pragma unroll
    for (int j = 0; j < N_INP; j += 4) {
      const float4 h4 = *(const float4*)&xl[tt * N_INP + j];
      a0 = fmaf(w[j],   h4.x, a0);
      a1 = fmaf(w[j+1], h4.y, a1);
      a2 = fmaf(w[j+2], h4.z, a2);
      a3 = fmaf(w[j+3], h4.w, a3);
    }
    out[((size_t)(tb*64 + tt) * N_MOD + n) * N_HID + t] = (a0+a1)+(a2+a3);
  }
}

// --------------------------------------------------------------------------
// Persistent stepping kernel: 256 WGs x 256 thr (R7-proven launch shape).
// WG (m=b>>2, q=b&3) owns rows [q*64,+64) of module m. Thread i: ro=i&63,
// jq=i>>6 (64-wide j-chunk).
//
// u-formulation: fb[m] = wm @ u[m], u[m,j] = sum_mm conn[m,mm]*hy_k[mm,j].
// The exchange buffer IS out_states: step k's producers publish hy_{k+1}
// into out_states[k+1] with sc1 stores (LLC-visible cross-XCD); consumers
// read out_states[k] with PLAIN CACHED loads — safe because each step's
// slice is a unique address (never reused within a replay; across replays
// ~196 MB/XCD of traffic guarantees eviction), and the counter-sync
// guarantees no read-before-publish.
//
// Per step k:
//   k>0: poll cnt_step >= 64k (1 thread, relaxed + s_sleep); __syncthreads;
//        gather u[i] = sum_mm conn[m,mm]*hy_k[mm,i]  (plain coalesced loads,
//        L2-dedup'd across the XCD's WGs)
//   hym[i] = hy_k[m,i]; __syncthreads
//   dual quarter-row matvecs: redr (h2h row . hym), redf (wm row . u) —
//   weights stream via float4 from warm L2 (no kernel boundaries, no
//   invalidates -> resident after step 1)
//   __syncthreads; wave 0: reduce, fb=(k==0?0:.), tanh Euler update;
//   publish hy->out_states[k+1] (sc1), hz/fb plain stores;
//   s_waitcnt vmcnt(0); lane0: cnt_mod[m] RMW, 4th arriver bumps cnt_step.
//
// Replay safety: counters memset each launch; xpre re-established each
// launch; k=0 skips poll+gather (fb=0 exactly, matching reference outs0=0).
// --------------------------------------------------------------------------
__global__ __launch_bounds__(256) void archnet_persist(
    const float* __restrict__ wm, const float* __restrict__ conn,
    const float* __restrict__ h2h, const float* __restrict__ bias,
    float* __restrict__ out_states, float* __restrict__ out_fb,
    unsigned* __restrict__ cnt_mod, unsigned* __restrict__ cnt_step)
{
  const int b  = blockIdx.x;        // 0..255
  const int m  = b >> 2;
  const int q  = b & 3;
  const int i  = threadIdx.x;       // 0..255
  const int ro = i & 63;
  const int jq = i >> 6;
  const int hu = q * 64 + ro;       // row owned by wave 0 lane ro

  __shared__ float hym[N_HID];
  __shared__ float u[N_HID];
  __shared__ float redr[256];
  __shared__ float redf[256];
  __shared__ float connrow[N_MOD];

  if (i < N_MOD) connrow[i] = conn[m * N_MOD + i];

  // ---- wave-0 persistent per-row state ----
  float hyv = 0.f, hzv = 0.f, bv = 0.f, xq = 0.f;
  if (i < 64) {
    const float* s0 = out_states + (size_t)m * 512;     // init (kernel above)
    hyv = s0[hu];
    hzv = s0[256 + hu];
    bv  = bias[m * N_HID + hu];
    xq  = out_fb[(size_t)m * N_HID + hu];               // xpre_0
  }

  for (int k = 0; k < T_STEPS; ++k) {
    const float* hyk = out_states + (size_t)k * (N_MOD * 512);

    // ---- poll + u-gather (k>0) ----
    if (k > 0) {
      if (i == 0) {
        const unsigned want = 64u * (unsigned)k;
        while (AG_LDU(cnt_step) < want) __builtin_amdgcn_s_sleep(2);
      }
      __syncthreads();            // all threads held until hy_k published
      float ua=0.f, ub=0.f, uc=0.f, ud=0.f;
#pragma unroll
      for (int mm = 0; mm < N_MOD; mm += 4) {
        ua = fmaf(connrow[mm+0], hyk[(size_t)(mm+0) * 512 + i], ua);
        ub = fmaf(connrow[mm+1], hyk[(size_t)(mm+1) * 512 + i], ub);
        uc = fmaf(connrow[mm+2], hyk[(size_t)(mm+2) * 512 + i], uc);
        ud = fmaf(connrow[mm+3], hyk[(size_t)(mm+3) * 512 + i], ud);
      }
      u[i] = (ua + ub) + (uc + ud);
    }
    hym[i] = hyk[(size_t)m * 512 + i];
    __syncthreads();              // hym + u (k>0) visible; connrow (k=0)

    // ---- dual quarter-row matvecs (weights from warm L2) ----
    {
      const int h = q * 64 + ro;
      const float* hrow = h2h + ((size_t)m * N_HID + h) * N_HID + jq * 64;
      const float* wrow = wm  + (size_t)h * N_HID + jq * 64;
      float r0=0.f, r1=0.f, r2=0.f, r3=0.f;
      float f0=0.f, f1=0.f, f2=0.f, f3=0.f;
#pragma unroll
      for (int j = 0; j < 64; j += 4) {
        const float4 a  = *(const float4*)(hrow + j);
        const float4 w4 = *(const float4*)(wrow + j);
        const float4 hv = *(const float4*)(&hym[jq * 64 + j]);
        const float4 uv = *(const float4*)(&u[jq * 64 + j]);
        r0 = fmaf(a.x, hv.x, r0);  f0 = fmaf(w4.x, uv.x, f0);
        r1 = fmaf(a.y, hv.y, r1);  f1 = fmaf(w4.y, uv.y, f1);
        r2 = fmaf(a.z, hv.z, r2);  f2 = fmaf(w4.z, uv.z, f2);
        r3 = fmaf(a.w, hv.w, r3);  f3 = fmaf(w4.w, uv.w, f3);
      }
      redr[i] = (r0 + r1) + (r2 + r3);
      redf[i] = (f0 + f1) + (f2 + f3);
    }
    __syncthreads();

    // ---- wave 0: reduce, update, publish, arrive ----
    if (i < 64) {
      const float r  = (redr[ro] + redr[ro + 64]) + (redr[ro + 128] + redr[ro + 192]);
      const float fb = (k == 0) ? 0.f
                     : (redf[ro] + redf[ro + 64]) + (redf[ro + 128] + redf[ro + 192]);
      const float pre = xq + r + bv + fb;
      const float th  = tanhf(pre);
      hzv = hzv + 0.01f * (th - hyv - hzv);     // GAMMA=EPS=1, DT=0.01
      hyv = hyv + 0.01f * hzv;

      float* o1 = out_states + (size_t)(k + 1) * (N_MOD * 512) + (size_t)m * 512;
      AG_STF(&o1[hu], hyv);                     // sc1: LLC-visible cross-XCD
      o1[256 + hu] = hzv;                       // plain (no cross-XCD reader)
      out_fb[((size_t)k * N_MOD + m) * N_HID + hu] = fb;   // overwrite xpre[k]
      asm volatile("s_waitcnt vmcnt(0)" ::: "memory");     // publish ACKed
      if (i == 0) {
        const unsigned old = AG_ADD(&cnt_mod[m * 16], 1u);
        if ((old & 3u) == 3u) AG_ADD(cnt_step, 1u);        // 4th WG of module
      }
      if (k + 1 < T_STEPS)
        xq = out_fb[((size_t)(k + 1) * N_MOD + m) * N_HID + hu];  // xpre[k+1]
    }
  }
}

// --------------------------------------------------------------------------
extern "C" void kernel_launch(void* const* d_in, const int* in_sizes, int n_in,
                              void* d_out, int out_size, void* d_ws, size_t ws_size,
                              hipStream_t stream) {
  const float* x    = (const float*)d_in[0];   // (2048,128)
  const float* init = (const float*)d_in[1];   // (64,2,256)
  const float* wmw  = (const float*)d_in[2];   // (256,256)
  const float* conn = (const float*)d_in[3];   // (64,64)
  const float* x2h  = (const float*)d_in[4];   // (64,256,128)
  const float* h2h  = (const float*)d_in[5];   // (64,256,256)
  const float* bias = (const float*)d_in[6];   // (64,256)

  float* out_states = (float*)d_out;                                        // (2049,64,2,256)
  float* out_fb     = out_states + (size_t)(T_STEPS+1) * N_MOD * 2 * N_HID; // (2048,64,256)

  // workspace: [cnt_step @0 | cnt_mod @256B (64 x stride-16 u32)], 8KB memset
  unsigned* cnt_step = (unsigned*)d_ws;
  unsigned* cnt_mod  = (unsigned*)((char*)d_ws + 256);
  hipMemsetAsync(d_ws, 0, 8192, stream);       // counters start at 0 each call

  init_kernel<<<64, 512, 0, stream>>>(init, out_states);
  xpre_kernel<<<dim3(T_STEPS/64, N_MOD), dim3(256), 0, stream>>>(x, x2h, out_fb);

  void* args[] = {
    (void*)&wmw, (void*)&conn, (void*)&h2h, (void*)&bias,
    (void*)&out_states, (void*)&out_fb, (void*)&cnt_mod, (void*)&cnt_step
  };
  hipLaunchCooperativeKernel((void*)archnet_persist, dim3(256), dim3(256),
                             args, 0, stream);
}

// Round 11
// 13445.859 us; speedup vs baseline: 3.4182x; 1.1148x over previous
//
#include <hip/hip_runtime.h>
#include <hip/hip_bf16.h>
#include <math.h>

#define T_STEPS 2048
#define N_MOD   64
#define N_HID   256
#define N_INP   128

typedef unsigned long long ull;

// Relaxed-ONLY agent-scope (sc1) ops — no acquire/release anywhere in the
// persistent kernel (R1/R7: agent-acquire emits cache invalidates, ~25us).
// An 8B sc1 store is atomic: a consumer can never see the tag without the
// value, so the tag equality check IS the release/acquire pairing.
__device__ __forceinline__ ull AG_LD64(const ull* p) {
  return __hip_atomic_load(p, __ATOMIC_RELAXED, __HIP_MEMORY_SCOPE_AGENT);
}
__device__ __forceinline__ void AG_ST64(ull* p, ull v) {
  __hip_atomic_store(p, v, __ATOMIC_RELAXED, __HIP_MEMORY_SCOPE_AGENT);
}

// --------------------------------------------------------------------------
// init: states_seq[0] = initial_states
// --------------------------------------------------------------------------
__global__ __launch_bounds__(512) void init_kernel(
    const float* __restrict__ init, float* __restrict__ out_states)
{
  const int idx = blockIdx.x * 512 + threadIdx.x;   // 64*512 = 32768 elems
  out_states[idx] = init[idx];
}

// --------------------------------------------------------------------------
// Pre-pass: xpre[t,n,h] = sum_i x2h[n,h,i] * x[t,i]  -> fb_seq region of d_out.
// Step kernels read xpre[t] then overwrite it with fb[t] (same thread,
// read-before-write; re-established every launch/replay).
// --------------------------------------------------------------------------
__global__ __launch_bounds__(256, 2) void xpre_kernel(
    const float* __restrict__ x, const float* __restrict__ x2h,
    float* __restrict__ out)
{
  __shared__ float xl[64 * N_INP];
  const int tb = blockIdx.x;
  const int n  = blockIdx.y;
  const int t  = threadIdx.x;

  const float4* xs  = (const float4*)(x + (size_t)tb * 64 * N_INP);
  float4*       xld = (float4*)xl;
  for (int k = t; k < 64 * N_INP / 4; k += 256) xld[k] = xs[k];

  float w[N_INP];
  const float* wrow = x2h + ((size_t)n * N_HID + t) * N_INP;
#pragma unroll
  for (int j = 0; j < N_INP; j += 4) {
    const float4 a = *(const float4*)(wrow + j);
    w[j] = a.x; w[j+1] = a.y; w[j+2] = a.z; w[j+3] = a.w;
  }
  __syncthreads();

  for (int tt = 0; tt < 64; ++tt) {
    float a0=0.f, a1=0.f, a2=0.f, a3=0.f;
#pragma unroll
    for (int j = 0; j < N_INP; j += 4) {
      const float4 h4 = *(const float4*)&xl[tt * N_INP + j];
      a0 = fmaf(w[j],   h4.x, a0);
      a1 = fmaf(w[j+1], h4.y, a1);
      a2 = fmaf(w[j+2], h4.z, a2);
      a3 = fmaf(w[j+3], h4.w, a3);
    }
    out[((size_t)(tb*64 + tt) * N_MOD + n) * N_HID + t] = (a0+a1)+(a2+a3);
  }
}

// --------------------------------------------------------------------------
// FALLBACK path (R6-proven, 16.4 ms): one kernel per timestep.
// Used only if the cooperative launch of archnet_persist is rejected.
// --------------------------------------------------------------------------
__global__ __launch_bounds__(256) void step_kernel(
    int k, const float* __restrict__ wm, const float* __restrict__ conn,
    const float* __restrict__ h2h, const float* __restrict__ bias,
    float* __restrict__ out_states, float* __restrict__ out_fb)
{
  const int b  = blockIdx.x;
  const int m  = b >> 2;
  const int q  = b & 3;
  const int i  = threadIdx.x;
  const int ro = i & 63;
  const int jq = i >> 6;

  __shared__ float hym[N_HID];
  __shared__ float u[N_HID];
  __shared__ float redr[256];
  __shared__ float redf[256];

  const float* hyk = out_states + (size_t)k * N_MOD * 512;

  hym[i] = hyk[(size_t)m * 512 + i];
  {
    float ua=0.f, ub=0.f, uc=0.f, ud=0.f;
#pragma unroll
    for (int mm = 0; mm < N_MOD; mm += 4) {
      ua = fmaf(conn[m * N_MOD + mm + 0], hyk[(size_t)(mm + 0) * 512 + i], ua);
      ub = fmaf(conn[m * N_MOD + mm + 1], hyk[(size_t)(mm + 1) * 512 + i], ub);
      uc = fmaf(conn[m * N_MOD + mm + 2], hyk[(size_t)(mm + 2) * 512 + i], uc);
      ud = fmaf(conn[m * N_MOD + mm + 3], hyk[(size_t)(mm + 3) * 512 + i], ud);
    }
    u[i] = (ua + ub) + (uc + ud);
  }
  float xq = 0.f, hyv = 0.f, hzv = 0.f, bv = 0.f;
  if (i < 64) {
    const int hu = q * 64 + i;
    xq  = out_fb[((size_t)k * N_MOD + m) * N_HID + hu];
    hyv = hyk[(size_t)m * 512 + hu];
    hzv = hyk[(size_t)m * 512 + 256 + hu];
    bv  = bias[m * N_HID + hu];
  }
  __syncthreads();

  {
    const int h = q * 64 + ro;
    const float* hrow = h2h + ((size_t)m * N_HID + h) * N_HID + jq * 64;
    const float* wrow = wm  + (size_t)h * N_HID + jq * 64;
    float r0=0.f, r1=0.f, r2=0.f, r3=0.f;
    float f0=0.f, f1=0.f, f2=0.f, f3=0.f;
#pragma unroll
    for (int j = 0; j < 64; j += 4) {
      const float4 a  = *(const float4*)(hrow + j);
      const float4 w4 = *(const float4*)(wrow + j);
      const float4 hv = *(const float4*)(&hym[jq * 64 + j]);
      const float4 uv = *(const float4*)(&u[jq * 64 + j]);
      r0 = fmaf(a.x, hv.x, r0);  f0 = fmaf(w4.x, uv.x, f0);
      r1 = fmaf(a.y, hv.y, r1);  f1 = fmaf(w4.y, uv.y, f1);
      r2 = fmaf(a.z, hv.z, r2);  f2 = fmaf(w4.z, uv.z, f2);
      r3 = fmaf(a.w, hv.w, r3);  f3 = fmaf(w4.w, uv.w, f3);
    }
    redr[i] = (r0 + r1) + (r2 + r3);
    redf[i] = (f0 + f1) + (f2 + f3);
  }
  __syncthreads();

  if (i < 64) {
    const int hu = q * 64 + i;
    const float r  = (redr[i] + redr[i + 64]) + (redr[i + 128] + redr[i + 192]);
    const float fb = (k == 0) ? 0.f
                   : (redf[i] + redf[i + 64]) + (redf[i + 128] + redf[i + 192]);
    const float pre = xq + r + bv + fb;
    const float th  = tanhf(pre);
    const float hzn = hzv + 0.01f * (th - hyv - hzv);
    const float hyn = hyv + 0.01f * hzn;
    const size_t ob = ((size_t)(k + 1) * N_MOD + m) * 512;
    out_states[ob + hu]       = hyn;
    out_states[ob + 256 + hu] = hzn;
    out_fb[((size_t)k * N_MOD + m) * N_HID + hu] = fb;
  }
}

// --------------------------------------------------------------------------
// Persistent stepping kernel: 256 WGs x 256 thr. WG (m=b>>2, q=b&3) owns
// rows [q*64,+64) of module m. Thread i: row r=i>>2, chunk c4=i&3 (64-wide);
// global row hq=q*64+r. Quad partials -> shfl_xor reduce.
//
// LDS budget ~67 KB (2 WGs/CU co-residency -> coop capacity check passes;
// R8/R10 lesson: grid==1-WG/CU bound gets rejected). Per-WG-unique h2h
// quarter lives in LDS (XOR-swizzled, conflict-free b128); globally-shared
// wm streams from L2 (256 KB chip-wide, all-CU reuse).
//
// Exchange: hbt[p][mm][h] = (tag<<32 | fp32 hy), parity p=tag&1. Publish =
// one relaxed 8B sc1 store; gather = retry-load until tag==k. No counters,
// fences, or waitcnt on the critical path.
//
// Overwrite safety: writer at iter k overwrites tag k-1 with k+1; passing
// gather(k) proves all WGs published k, hence finished gather(k-1).
// hym parity-buffered; u_lds single (own-module tags k+1 require own 4
// waves past their matvec-k reads). Replay safety: hbt memset each launch.
// --------------------------------------------------------------------------
__global__ __launch_bounds__(256) void archnet_persist(
    const float* __restrict__ init, const float* __restrict__ wm,
    const float* __restrict__ conn, const float* __restrict__ h2h,
    const float* __restrict__ bias,
    float* __restrict__ out_states, float* __restrict__ out_fb,
    ull* __restrict__ hbt)
{
  __shared__ float wA[64 * 256];      // 64 KB h2h quarter, swizzled
  __shared__ float hym[2][N_HID];     // 2 KB, parity-buffered hy_k
  __shared__ float u_lds[N_HID];      // 1 KB
  __shared__ float connrow[N_MOD];    // 256 B

  const int b  = blockIdx.x;          // 0..255
  const int m  = b >> 2;
  const int q  = b & 3;
  const int i  = threadIdx.x;         // 0..255
  const int r  = i >> 2;              // local row 0..63
  const int c4 = i & 3;               // 64-col chunk
  const int hq = q * 64 + r;          // global row

  if (i < N_MOD) connrow[i] = conn[m * N_MOD + i];
  u_lds[i] = 0.f;                     // k=0: fb term reads zeros
  hym[0][i] = init[(size_t)m * 512 + i];

  // ---- stage h2h quarter -> LDS, swizzled: group g at row rr -> g^(rr&7) ----
  for (int idx = i; idx < 64 * 64; idx += 256) {   // 64 rows x 64 f4-groups
    const int rr = idx >> 6, g = idx & 63;
    const float4 a = *(const float4*)(h2h + ((size_t)m * N_HID + q * 64 + rr) * N_HID + g * 4);
    *(float4*)&wA[rr * 256 + (g ^ (rr & 7)) * 4] = a;
  }

  // ---- per-row persistent state (c4==0 lanes) ----
  float hyv = 0.f, hzv = 0.f, bv = 0.f, xq = 0.f;
  if (c4 == 0) {
    hyv = init[(size_t)m * 512 + hq];
    hzv = init[(size_t)m * 512 + 256 + hq];
    bv  = bias[m * N_HID + hq];
    xq  = out_fb[(size_t)m * N_HID + hq];             // xpre_0
  }
  __syncthreads();

  const float* wrow = wm + (size_t)hq * N_HID + c4 * 64;  // L2-resident

  for (int k = 0; k < T_STEPS; ++k) {
    const int pr = k & 1, pw = (k + 1) & 1;

    // ---- gather (k>0): 64 tagged slots -> u_i; sibling rows -> hym[pr] ----
    if (k > 0) {
      ull* hb = hbt + (size_t)pr * (N_MOD * N_HID);
      const unsigned want = (unsigned)k;
      float acc = 0.f;
      ull B0[16], B1[16];
#define GISSUE(BUF, BASE) \
      _Pragma("unroll") for (int t2 = 0; t2 < 16; ++t2) \
        BUF[t2] = AG_LD64(&hb[(size_t)((BASE) + t2) * N_HID + i]);
#define GRESOLVE(BUF, BASE) { \
      bool again = true; \
      while (again) { again = false; \
        _Pragma("unroll") for (int t2 = 0; t2 < 16; ++t2) { \
          if ((unsigned)(BUF[t2] >> 32) != want) { \
            BUF[t2] = AG_LD64(&hb[(size_t)((BASE) + t2) * N_HID + i]); again = true; } } } \
      _Pragma("unroll") for (int t2 = 0; t2 < 16; t2 += 4) { \
        const float4 cf = *(const float4*)&connrow[(BASE) + t2]; \
        acc = fmaf(cf.x, __uint_as_float((unsigned)BUF[t2+0]), acc); \
        acc = fmaf(cf.y, __uint_as_float((unsigned)BUF[t2+1]), acc); \
        acc = fmaf(cf.z, __uint_as_float((unsigned)BUF[t2+2]), acc); \
        acc = fmaf(cf.w, __uint_as_float((unsigned)BUF[t2+3]), acc); } }
      GISSUE(B0, 0); GISSUE(B1, 16);
      GRESOLVE(B0, 0);  GISSUE(B0, 32);
      GRESOLVE(B1, 16); GISSUE(B1, 48);
      GRESOLVE(B0, 32);
      GRESOLVE(B1, 48);
#undef GISSUE
#undef GRESOLVE
      u_lds[i] = acc;

      // own-module row i (sibling quarters only; own rows written locally)
      if ((i >> 6) != q) {
        ull v = AG_LD64(&hb[(size_t)m * N_HID + i]);
        while ((unsigned)(v >> 32) != want) v = AG_LD64(&hb[(size_t)m * N_HID + i]);
        hym[pr][i] = __uint_as_float((unsigned)v);
      }
    }
    __syncthreads();   // u + hym[pr] ready; orders LDS reads vs next writes

    // ---- dual quarter-row matvecs: h2h from LDS, wm from L2 ----
    float rsum, fsum;
    {
      float r0=0.f, r1=0.f, r2=0.f, r3=0.f;
      float f0=0.f, f1=0.f, f2=0.f, f3=0.f;
#pragma unroll
      for (int j = 0; j < 16; ++j) {
        const int gs = ((c4 * 16 + j) ^ (r & 7)) * 4;
        const float4 a  = *(const float4*)&wA[r * 256 + gs];
        const float4 w4 = *(const float4*)(wrow + j * 4);
        const float4 hv = *(const float4*)&hym[pr][c4 * 64 + j * 4];
        const float4 uv = *(const float4*)&u_lds[c4 * 64 + j * 4];
        r0 = fmaf(a.x, hv.x, r0);  f0 = fmaf(w4.x, uv.x, f0);
        r1 = fmaf(a.y, hv.y, r1);  f1 = fmaf(w4.y, uv.y, f1);
        r2 = fmaf(a.z, hv.z, r2);  f2 = fmaf(w4.z, uv.z, f2);
        r3 = fmaf(a.w, hv.w, r3);  f3 = fmaf(w4.w, uv.w, f3);
      }
      rsum = (r0 + r1) + (r2 + r3);
      fsum = (f0 + f1) + (f2 + f3);
      rsum += __shfl_xor(rsum, 1); rsum += __shfl_xor(rsum, 2);
      fsum += __shfl_xor(fsum, 1); fsum += __shfl_xor(fsum, 2);
    }

    // ---- c4==0 lanes: update, publish, outputs ----
    if (c4 == 0) {
      const float fb  = (k == 0) ? 0.f : fsum;
      const float pre = xq + rsum + bv + fb;
      const float th  = tanhf(pre);
      hzv = hzv + 0.01f * (th - hyv - hzv);     // GAMMA=EPS=1, DT=0.01
      hyv = hyv + 0.01f * hzv;

      // publish hy_{k+1} (tag k+1): single atomic 8B sc1 store, no waitcnt
      AG_ST64(&hbt[(size_t)pw * (N_MOD * N_HID) + (size_t)m * N_HID + hq],
              ((ull)(unsigned)(k + 1) << 32) | (ull)__float_as_uint(hyv));
      hym[pw][hq] = hyv;                        // own row for next iter

      // outputs (plain cached stores, off the critical path)
      const size_t ob = ((size_t)(k + 1) * N_MOD + m) * 512;
      out_states[ob + hq]       = hyv;
      out_states[ob + 256 + hq] = hzv;
      out_fb[((size_t)k * N_MOD + m) * N_HID + hq] = fb;   // overwrite xpre[k]
      if (k + 1 < T_STEPS)
        xq = out_fb[((size_t)(k + 1) * N_MOD + m) * N_HID + hq];
    }
    // no trailing barrier: next gather is tag-gated; hym[pw] reads occur
    // only after the next iteration's barrier.
  }
}

// --------------------------------------------------------------------------
extern "C" void kernel_launch(void* const* d_in, const int* in_sizes, int n_in,
                              void* d_out, int out_size, void* d_ws, size_t ws_size,
                              hipStream_t stream) {
  const float* x    = (const float*)d_in[0];   // (2048,128)
  const float* init = (const float*)d_in[1];   // (64,2,256)
  const float* wmw  = (const float*)d_in[2];   // (256,256)
  const float* conn = (const float*)d_in[3];   // (64,64)
  const float* x2h  = (const float*)d_in[4];   // (64,256,128)
  const float* h2h  = (const float*)d_in[5];   // (64,256,256)
  const float* bias = (const float*)d_in[6];   // (64,256)

  float* out_states = (float*)d_out;                                        // (2049,64,2,256)
  float* out_fb     = out_states + (size_t)(T_STEPS+1) * N_MOD * 2 * N_HID; // (2048,64,256)

  // workspace: tagged hy exchange, double-buffered: 2*64*256*8B = 256 KB.
  // memset -> stale tag 0 != any wanted tag (1..2048): replay-deterministic.
  ull* hbt = (ull*)d_ws;
  hipMemsetAsync(d_ws, 0, (size_t)2 * N_MOD * N_HID * 8, stream);

  init_kernel<<<64, 512, 0, stream>>>(init, out_states);
  xpre_kernel<<<dim3(T_STEPS/64, N_MOD), dim3(256), 0, stream>>>(x, x2h, out_fb);

  void* args[] = {
    (void*)&init, (void*)&wmw, (void*)&conn, (void*)&h2h, (void*)&bias,
    (void*)&out_states, (void*)&out_fb, (void*)&hbt
  };
  hipError_t err = hipLaunchCooperativeKernel((void*)archnet_persist,
                                              dim3(256), dim3(256),
                                              args, 0, stream);
  if (err != hipSuccess) {
    // Fallback: kernel-per-step (R6-proven). Deterministic: same device ->
    // same path every call; both paths compute identical results.
    for (int k = 0; k < T_STEPS; ++k)
      step_kernel<<<256, 256, 0, stream>>>(k, wmw, conn, h2h, bias,
                                           out_states, out_fb);
  }
}

// Round 12
// 10415.091 us; speedup vs baseline: 4.4129x; 1.2910x over previous
//
#include <hip/hip_runtime.h>
#include <hip/hip_bf16.h>
#include <math.h>

#define T_STEPS 2048
#define N_MOD   64
#define N_HID   256
#define N_INP   128

typedef unsigned long long ull;

// Relaxed-ONLY agent-scope (sc1) ops — no acquire/release anywhere in the
// persistent kernel (R1/R7: agent-acquire emits cache invalidates, ~25us;
// R7 acq_rel barrier ≈ 25us). Ordering: each wave's s_waitcnt vmcnt(0)
// (implicit in __syncthreads) ACKs sc1 stores at the LLC coherence point
// before the flag store is issued.
__device__ __forceinline__ void AG_STF(float* p, float v) {
  __hip_atomic_store(p, v, __ATOMIC_RELAXED, __HIP_MEMORY_SCOPE_AGENT);
}
__device__ __forceinline__ void AG_STU(unsigned* p, unsigned v) {
  __hip_atomic_store(p, v, __ATOMIC_RELAXED, __HIP_MEMORY_SCOPE_AGENT);
}
__device__ __forceinline__ unsigned AG_LDU(const unsigned* p) {
  return __hip_atomic_load(p, __ATOMIC_RELAXED, __HIP_MEMORY_SCOPE_AGENT);
}

// --------------------------------------------------------------------------
// init: states_seq[0] = initial_states
// --------------------------------------------------------------------------
__global__ __launch_bounds__(512) void init_kernel(
    const float* __restrict__ init, float* __restrict__ out_states)
{
  const int idx = blockIdx.x * 512 + threadIdx.x;   // 64*512 = 32768 elems
  out_states[idx] = init[idx];
}

// --------------------------------------------------------------------------
// Pre-pass: xpre[t,n,h] = sum_i x2h[n,h,i] * x[t,i]  -> fb_seq region of d_out.
// Step kernels read xpre[t] then overwrite it with fb[t] (same thread,
// read-before-write; re-established every launch/replay).
// --------------------------------------------------------------------------
__global__ __launch_bounds__(256, 2) void xpre_kernel(
    const float* __restrict__ x, const float* __restrict__ x2h,
    float* __restrict__ out)
{
  __shared__ float xl[64 * N_INP];
  const int tb = blockIdx.x;
  const int n  = blockIdx.y;
  const int t  = threadIdx.x;

  const float4* xs  = (const float4*)(x + (size_t)tb * 64 * N_INP);
  float4*       xld = (float4*)xl;
  for (int k = t; k < 64 * N_INP / 4; k += 256) xld[k] = xs[k];

  float w[N_INP];
  const float* wrow = x2h + ((size_t)n * N_HID + t) * N_INP;
#pragma unroll
  for (int j = 0; j < N_INP; j += 4) {
    const float4 a = *(const float4*)(wrow + j);
    w[j] = a.x; w[j+1] = a.y; w[j+2] = a.z; w[j+3] = a.w;
  }
  __syncthreads();

  for (int tt = 0; tt < 64; ++tt) {
    float a0=0.f, a1=0.f, a2=0.f, a3=0.f;
#pragma unroll
    for (int j = 0; j < N_INP; j += 4) {
      const float4 h4 = *(const float4*)&xl[tt * N_INP + j];
      a0 = fmaf(w[j],   h4.x, a0);
      a1 = fmaf(w[j+1], h4.y, a1);
      a2 = fmaf(w[j+2], h4.z, a2);
      a3 = fmaf(w[j+3], h4.w, a3);
    }
    out[((size_t)(tb*64 + tt) * N_MOD + n) * N_HID + t] = (a0+a1)+(a2+a3);
  }
}

// --------------------------------------------------------------------------
// FALLBACK (R6-proven, 16.4 ms): one kernel per timestep. Used only if the
// cooperative launch is rejected (R8/R10 failure mode).
// --------------------------------------------------------------------------
__global__ __launch_bounds__(256) void step_kernel(
    int k, const float* __restrict__ wm, const float* __restrict__ conn,
    const float* __restrict__ h2h, const float* __restrict__ bias,
    float* __restrict__ out_states, float* __restrict__ out_fb)
{
  const int b  = blockIdx.x;
  const int m  = b >> 2;
  const int q  = b & 3;
  const int i  = threadIdx.x;
  const int ro = i & 63;
  const int jq = i >> 6;

  __shared__ float hym[N_HID];
  __shared__ float u[N_HID];
  __shared__ float redr[256];
  __shared__ float redf[256];

  const float* hyk = out_states + (size_t)k * N_MOD * 512;

  hym[i] = hyk[(size_t)m * 512 + i];
  {
    float ua=0.f, ub=0.f, uc=0.f, ud=0.f;
#pragma unroll
    for (int mm = 0; mm < N_MOD; mm += 4) {
      ua = fmaf(conn[m * N_MOD + mm + 0], hyk[(size_t)(mm + 0) * 512 + i], ua);
      ub = fmaf(conn[m * N_MOD + mm + 1], hyk[(size_t)(mm + 1) * 512 + i], ub);
      uc = fmaf(conn[m * N_MOD + mm + 2], hyk[(size_t)(mm + 2) * 512 + i], uc);
      ud = fmaf(conn[m * N_MOD + mm + 3], hyk[(size_t)(mm + 3) * 512 + i], ud);
    }
    u[i] = (ua + ub) + (uc + ud);
  }
  float xq = 0.f, hyv = 0.f, hzv = 0.f, bv = 0.f;
  if (i < 64) {
    const int hu = q * 64 + i;
    xq  = out_fb[((size_t)k * N_MOD + m) * N_HID + hu];
    hyv = hyk[(size_t)m * 512 + hu];
    hzv = hyk[(size_t)m * 512 + 256 + hu];
    bv  = bias[m * N_HID + hu];
  }
  __syncthreads();

  {
    const int h = q * 64 + ro;
    const float* hrow = h2h + ((size_t)m * N_HID + h) * N_HID + jq * 64;
    const float* wrow = wm  + (size_t)h * N_HID + jq * 64;
    float r0=0.f, r1=0.f, r2=0.f, r3=0.f;
    float f0=0.f, f1=0.f, f2=0.f, f3=0.f;
#pragma unroll
    for (int j = 0; j < 64; j += 4) {
      const float4 a  = *(const float4*)(hrow + j);
      const float4 w4 = *(const float4*)(wrow + j);
      const float4 hv = *(const float4*)(&hym[jq * 64 + j]);
      const float4 uv = *(const float4*)(&u[jq * 64 + j]);
      r0 = fmaf(a.x, hv.x, r0);  f0 = fmaf(w4.x, uv.x, f0);
      r1 = fmaf(a.y, hv.y, r1);  f1 = fmaf(w4.y, uv.y, f1);
      r2 = fmaf(a.z, hv.z, r2);  f2 = fmaf(w4.z, uv.z, f2);
      r3 = fmaf(a.w, hv.w, r3);  f3 = fmaf(w4.w, uv.w, f3);
    }
    redr[i] = (r0 + r1) + (r2 + r3);
    redf[i] = (f0 + f1) + (f2 + f3);
  }
  __syncthreads();

  if (i < 64) {
    const int hu = q * 64 + i;
    const float r  = (redr[i] + redr[i + 64]) + (redr[i + 128] + redr[i + 192]);
    const float fb = (k == 0) ? 0.f
                   : (redf[i] + redf[i + 64]) + (redf[i + 128] + redf[i + 192]);
    const float pre = xq + r + bv + fb;
    const float th  = tanhf(pre);
    const float hzn = hzv + 0.01f * (th - hyv - hzv);
    const float hyn = hyv + 0.01f * hzn;
    const size_t ob = ((size_t)(k + 1) * N_MOD + m) * 512;
    out_states[ob + hu]       = hyn;
    out_states[ob + 256 + hu] = hzn;
    out_fb[((size_t)k * N_MOD + m) * N_HID + hu] = fb;
  }
}

// --------------------------------------------------------------------------
// Persistent stepping kernel: 256 WGs x 256 thr (~67KB LDS -> 2 WG/CU ->
// coop capacity check passes). WG (m=b>>2, q=b&3) owns rows [q*64,+64) of
// module m. Thread i: row r=i>>2, chunk c4=i&3; global row hq=q*64+r.
//
// u-formulation: fb[m] = wm @ u[m], u[m,j] = sum_mm conn[m,mm]*hy_k[mm,j].
//
// Exchange = out_states itself (written once, sc1). Unique address per step
// -> consumers use PLAIN CACHED loads (L2-dedup across the XCD's 32 WGs;
// R11's per-element tagged sc1 gather was LLC-BW-bound at 33 MB/step).
// Staleness impossible: address never cached before the sc1 write lands
// (and across replays the values are bit-identical + poison epoch evicted).
//
// Sync: flags[256] monotone per-WG step counters (sc1). Producer: sc1 hy
// stores -> __syncthreads (each wave drains vmcnt -> stores ACKed at LLC)
// -> one sc1 flag store. Consumer: wave-0 lanes poll 4 flags each
// (relaxed sc1 + s_sleep + ballot). No RMWs, no fences, no tags.
//
// LDS: h2h quarter (64KB, XOR-swizzled g^=row&7: b128 reads at the 8-cycle
// floor). hym/u padded to 68-float chunk stride (68 mod 32 = 4 -> the four
// c4 chunks hit four distinct bank groups; 68 floats = 17x16B so float4
// stays aligned) — fixes R11's 1.2e9 bank-conflict cycles.
// wm streams from L2 (256KB chip-shared, hot after step 1).
// --------------------------------------------------------------------------
__global__ __launch_bounds__(256) void archnet_persist(
    const float* __restrict__ init, const float* __restrict__ wm,
    const float* __restrict__ conn, const float* __restrict__ h2h,
    const float* __restrict__ bias,
    float* __restrict__ out_states, float* __restrict__ out_fb,
    unsigned* __restrict__ flags)
{
  __shared__ float wA[64 * 256];      // 64 KB h2h quarter, swizzled
  __shared__ float hym_l[4 * 68];     // padded hy_k[m]
  __shared__ float u_l[4 * 68];       // padded u
  __shared__ float connrow[N_MOD];

  const int b  = blockIdx.x;          // 0..255
  const int m  = b >> 2;
  const int q  = b & 3;
  const int i  = threadIdx.x;         // 0..255
  const int r  = i >> 2;              // local row 0..63
  const int c4 = i & 3;               // 64-col chunk
  const int hq = q * 64 + r;          // global row
  const int pi = (i >> 6) * 68 + (i & 63);   // padded index for h-column i

  if (i < N_MOD) connrow[i] = conn[m * N_MOD + i];
  u_l[pi] = 0.f;                      // k=0: fb reads zeros

  // ---- stage h2h quarter -> LDS, swizzled ----
  for (int idx = i; idx < 64 * 64; idx += 256) {   // 64 rows x 64 f4-groups
    const int rr = idx >> 6, g = idx & 63;
    const float4 a = *(const float4*)(h2h + ((size_t)m * N_HID + q * 64 + rr) * N_HID + g * 4);
    *(float4*)&wA[rr * 256 + (g ^ (rr & 7)) * 4] = a;
  }

  // ---- per-row persistent state (c4==0 lanes) ----
  float hyv = 0.f, hzv = 0.f, bv = 0.f, xq = 0.f;
  if (c4 == 0) {
    hyv = init[(size_t)m * 512 + hq];
    hzv = init[(size_t)m * 512 + 256 + hq];
    bv  = bias[m * N_HID + hq];
    xq  = out_fb[(size_t)m * N_HID + hq];             // xpre_0
  }

  const float* wrow = wm + (size_t)hq * N_HID + c4 * 64;  // L2-resident

  for (int k = 0; k < T_STEPS; ++k) {
    // ---- (a) poll: all 256 producer flags >= k ----
    if (k > 0 && i < 64) {
      const unsigned kk = (unsigned)k;
      for (;;) {
        const unsigned f0 = AG_LDU(&flags[i * 4 + 0]);
        const unsigned f1 = AG_LDU(&flags[i * 4 + 1]);
        const unsigned f2 = AG_LDU(&flags[i * 4 + 2]);
        const unsigned f3 = AG_LDU(&flags[i * 4 + 3]);
        if (!__any(f0 < kk || f1 < kk || f2 < kk || f3 < kk)) break;
        __builtin_amdgcn_s_sleep(1);
      }
    }
    __syncthreads();                  // poll done; also orders LDS reuse

    // ---- (b) hym + u-gather: plain cached loads (L2-dedup'd) ----
    const float* hyk = out_states + (size_t)k * (N_MOD * 512);
    hym_l[pi] = hyk[(size_t)m * 512 + i];
    if (k > 0) {
      float ua=0.f, ub=0.f, uc=0.f, ud=0.f;
#pragma unroll
      for (int mm = 0; mm < N_MOD; mm += 4) {
        ua = fmaf(connrow[mm+0], hyk[(size_t)(mm+0) * 512 + i], ua);
        ub = fmaf(connrow[mm+1], hyk[(size_t)(mm+1) * 512 + i], ub);
        uc = fmaf(connrow[mm+2], hyk[(size_t)(mm+2) * 512 + i], uc);
        ud = fmaf(connrow[mm+3], hyk[(size_t)(mm+3) * 512 + i], ud);
      }
      u_l[pi] = (ua + ub) + (uc + ud);
    }
    __syncthreads();                  // hym + u visible

    // ---- dual quarter-row matvecs (wA LDS-swizzled, wm L2, vecs padded) ----
    float rsum, fsum;
    {
      float r0=0.f, r1=0.f, r2=0.f, r3=0.f;
      float f0=0.f, f1=0.f, f2=0.f, f3=0.f;
#pragma unroll
      for (int j = 0; j < 16; ++j) {
        const int gs = ((c4 * 16 + j) ^ (r & 7)) * 4;
        const float4 a  = *(const float4*)&wA[r * 256 + gs];
        const float4 w4 = *(const float4*)(wrow + j * 4);
        const float4 hv = *(const float4*)&hym_l[c4 * 68 + j * 4];
        const float4 uv = *(const float4*)&u_l[c4 * 68 + j * 4];
        r0 = fmaf(a.x, hv.x, r0);  f0 = fmaf(w4.x, uv.x, f0);
        r1 = fmaf(a.y, hv.y, r1);  f1 = fmaf(w4.y, uv.y, f1);
        r2 = fmaf(a.z, hv.z, r2);  f2 = fmaf(w4.z, uv.z, f2);
        r3 = fmaf(a.w, hv.w, r3);  f3 = fmaf(w4.w, uv.w, f3);
      }
      rsum = (r0 + r1) + (r2 + r3);
      fsum = (f0 + f1) + (f2 + f3);
      rsum += __shfl_xor(rsum, 1); rsum += __shfl_xor(rsum, 2);
      fsum += __shfl_xor(fsum, 1); fsum += __shfl_xor(fsum, 2);
    }

    // ---- (c) update + sc1 publish (only hy before the drain barrier) ----
    float fbv = 0.f;
    if (c4 == 0) {
      fbv = (k == 0) ? 0.f : fsum;
      const float pre = xq + rsum + bv + fbv;
      const float th  = tanhf(pre);
      hzv = hzv + 0.01f * (th - hyv - hzv);     // GAMMA=EPS=1, DT=0.01
      hyv = hyv + 0.01f * hzv;
      AG_STF(out_states + (size_t)(k + 1) * (N_MOD * 512) + (size_t)m * 512 + hq,
             hyv);                              // sc1 -> LLC, cross-XCD visible
    }
    __syncthreads();   // every wave drains vmcnt(0): hy stores ACKed at LLC
    if (i == 0) AG_STU(&flags[b], (unsigned)(k + 1));

    // ---- plain output stores + xpre prefetch (drain at NEXT step's poll) ----
    if (c4 == 0) {
      const size_t ob = ((size_t)(k + 1) * N_MOD + m) * 512;
      out_states[ob + 256 + hq] = hzv;
      out_fb[((size_t)k * N_MOD + m) * N_HID + hq] = fbv;  // overwrite xpre[k]
      if (k + 1 < T_STEPS)
        xq = out_fb[((size_t)(k + 1) * N_MOD + m) * N_HID + hq];
    }
  }
}

// --------------------------------------------------------------------------
extern "C" void kernel_launch(void* const* d_in, const int* in_sizes, int n_in,
                              void* d_out, int out_size, void* d_ws, size_t ws_size,
                              hipStream_t stream) {
  const float* x    = (const float*)d_in[0];   // (2048,128)
  const float* init = (const float*)d_in[1];   // (64,2,256)
  const float* wmw  = (const float*)d_in[2];   // (256,256)
  const float* conn = (const float*)d_in[3];   // (64,64)
  const float* x2h  = (const float*)d_in[4];   // (64,256,128)
  const float* h2h  = (const float*)d_in[5];   // (64,256,256)
  const float* bias = (const float*)d_in[6];   // (64,256)

  float* out_states = (float*)d_out;                                        // (2049,64,2,256)
  float* out_fb     = out_states + (size_t)(T_STEPS+1) * N_MOD * 2 * N_HID; // (2048,64,256)

  // workspace: flags[256] monotone per-WG counters, memset each launch.
  unsigned* flags = (unsigned*)d_ws;
  hipMemsetAsync(d_ws, 0, 1024, stream);

  init_kernel<<<64, 512, 0, stream>>>(init, out_states);
  xpre_kernel<<<dim3(T_STEPS/64, N_MOD), dim3(256), 0, stream>>>(x, x2h, out_fb);

  void* args[] = {
    (void*)&init, (void*)&wmw, (void*)&conn, (void*)&h2h, (void*)&bias,
    (void*)&out_states, (void*)&out_fb, (void*)&flags
  };
  hipError_t err = hipLaunchCooperativeKernel((void*)archnet_persist,
                                              dim3(256), dim3(256),
                                              args, 0, stream);
  if (err != hipSuccess) {
    // Fallback: kernel-per-step (R6-proven). Same math, same outputs.
    for (int k = 0; k < T_STEPS; ++k)
      step_kernel<<<256, 256, 0, stream>>>(k, wmw, conn, h2h, bias,
                                           out_states, out_fb);
  }
}